// Round 3
// baseline (363.159 us; speedup 1.0000x reference)
//
#include <hip/hip_runtime.h>
#include <hip/hip_bf16.h>

typedef __bf16 bf16x8 __attribute__((ext_vector_type(8)));
typedef float  f32x4  __attribute__((ext_vector_type(4)));

#define HH    8
#define NN    4096
#define FIN   512
#define FOUT  64
#define ALPHA 0.2f

// ---------------------------------------------------------------------------
// k0: W[h][f][o] (fp32) -> WT[h][o][f] (bf16)
// ---------------------------------------------------------------------------
__global__ void k_transpose_w(const float* __restrict__ Wsrc,
                              __hip_bfloat16* __restrict__ WT) {
    int idx = blockIdx.x * blockDim.x + threadIdx.x;  // H*FIN*FOUT = 262144
    int h   = idx / (FIN * FOUT);
    int rem = idx % (FIN * FOUT);
    int f   = rem / FOUT;
    int o   = rem % FOUT;
    WT[((size_t)h * FOUT + o) * FIN + f] = __float2bfloat16(Wsrc[idx]);
}

// ---------------------------------------------------------------------------
// k1: projection. Per head h: Wh = feat(4096x512,fp32) @ W[h](512x64), fp32 acc
// via bf16 MFMA (in-register fp32->bf16 convert of the A operand).
// Writes WhT[h][o][n] (bf16) and src[h][n], dst[h][n] (fp32).
// Wave = 16 rows x 64 cols via 4x mfma_f32_16x16x32_bf16.
// A-frag: lane holds A[m=lane&15][k=quad*8+j] ; B-frag: B[n=lane&15][k=quad*8+j]
// C/D   : lane holds C[row=quad*4+r][col=lane&15]   (HW-verified layouts)
// ---------------------------------------------------------------------------
__global__ __launch_bounds__(256) void k_proj(
    const float* __restrict__ feat,
    const __hip_bfloat16* __restrict__ WT,
    const float* __restrict__ a_src,
    const float* __restrict__ a_dst,
    __hip_bfloat16* __restrict__ WhT,
    float* __restrict__ srcv, float* __restrict__ dstv) {
    const int h     = blockIdx.y;
    const int wave  = threadIdx.x >> 6;
    const int lane  = threadIdx.x & 63;
    const int row16 = lane & 15;
    const int quad  = lane >> 4;
    const int nbase = blockIdx.x * 64 + wave * 16;

    const unsigned short* WTu = (const unsigned short*)WT + (size_t)h * FOUT * FIN;
    const float* featrow = feat + (size_t)(nbase + row16) * FIN + quad * 8;

    f32x4 acc[4] = {};
    for (int k0 = 0; k0 < FIN; k0 += 32) {
        float4 f0 = *(const float4*)(featrow + k0);
        float4 f1 = *(const float4*)(featrow + k0 + 4);
        bf16x8 a;
        a[0] = (__bf16)f0.x; a[1] = (__bf16)f0.y; a[2] = (__bf16)f0.z; a[3] = (__bf16)f0.w;
        a[4] = (__bf16)f1.x; a[5] = (__bf16)f1.y; a[6] = (__bf16)f1.z; a[7] = (__bf16)f1.w;
#pragma unroll
        for (int ot = 0; ot < 4; ++ot) {
            bf16x8 b = *(const bf16x8*)(WTu + (size_t)(ot * 16 + row16) * FIN + k0 + quad * 8);
            acc[ot] = __builtin_amdgcn_mfma_f32_16x16x32_bf16(a, b, acc[ot], 0, 0, 0);
        }
    }

    // Write WhT[h][o][n] in bf16 (B operand of the attention GEMM)
#pragma unroll
    for (int ot = 0; ot < 4; ++ot) {
        int o = ot * 16 + row16;
#pragma unroll
        for (int r = 0; r < 4; ++r) {
            int n = nbase + quad * 4 + r;
            WhT[((size_t)h * FOUT + o) * NN + n] = __float2bfloat16(acc[ot][r]);
        }
    }

    // src[h][n] = Wh[n][:] . a_src[h], dst likewise — fp32 accumulators x fp32 a.
    float asv[4], adv[4];
#pragma unroll
    for (int ot = 0; ot < 4; ++ot) {
        asv[ot] = a_src[h * FOUT + ot * 16 + row16];
        adv[ot] = a_dst[h * FOUT + ot * 16 + row16];
    }
#pragma unroll
    for (int r = 0; r < 4; ++r) {
        float ss = 0.f, dd = 0.f;
#pragma unroll
        for (int ot = 0; ot < 4; ++ot) {
            ss += acc[ot][r] * asv[ot];
            dd += acc[ot][r] * adv[ot];
        }
        // reduce over the 16 lanes (bits 0..3) sharing this row
        ss += __shfl_xor(ss, 1); ss += __shfl_xor(ss, 2);
        ss += __shfl_xor(ss, 4); ss += __shfl_xor(ss, 8);
        dd += __shfl_xor(dd, 1); dd += __shfl_xor(dd, 2);
        dd += __shfl_xor(dd, 4); dd += __shfl_xor(dd, 8);
        if (row16 == 0) {
            int n = nbase + quad * 4 + r;
            srcv[h * NN + n] = ss;
            dstv[h * NN + n] = dd;
        }
    }
}

// ---------------------------------------------------------------------------
// k2: flash-style masked attention + ELU.
// Block = 4 waves, one head; wave = 16 rows (i) x 64 cols (o).
// No max subtraction needed: e in ~[-10,10] so exp(e) is fp32-safe; masked
// entries contribute exactly 0 (matches ref's exp(-1e9 - m) underflow).
// lsum accumulates the bf16-quantized p so numerator/denominator match.
// ---------------------------------------------------------------------------
__global__ __launch_bounds__(256) void k_flash(
    const int* __restrict__ adj,
    const float* __restrict__ srcv, const float* __restrict__ dstv,
    const __hip_bfloat16* __restrict__ WhT,
    float* __restrict__ out) {
    const int h     = blockIdx.y;
    const int wave  = threadIdx.x >> 6;
    const int lane  = threadIdx.x & 63;
    const int row16 = lane & 15;
    const int quad  = lane >> 4;
    const int i     = blockIdx.x * 64 + wave * 16 + row16;

    const float           si     = srcv[h * NN + i];
    const unsigned short* WhTu   = (const unsigned short*)WhT + (size_t)h * FOUT * NN;
    const int*            adjrow = adj + (size_t)i * NN;
    const float*          dsth   = dstv + h * NN;

    f32x4 acc[4] = {};
    float lsum = 0.f;

    for (int j0 = 0; j0 < NN; j0 += 32) {
        int jj = j0 + quad * 8;
        int4   a0 = *(const int4*)(adjrow + jj);
        int4   a1 = *(const int4*)(adjrow + jj + 4);
        float4 d0 = *(const float4*)(dsth + jj);
        float4 d1 = *(const float4*)(dsth + jj + 4);
        const float dv[8] = {d0.x, d0.y, d0.z, d0.w, d1.x, d1.y, d1.z, d1.w};
        const int   av[8] = {a0.x, a0.y, a0.z, a0.w, a1.x, a1.y, a1.z, a1.w};
        bf16x8 afrag;
#pragma unroll
        for (int k = 0; k < 8; ++k) {
            float t  = si + dv[k];
            float e  = t > 0.f ? t : ALPHA * t;
            float pk = av[k] > 0 ? __expf(e) : 0.f;
            __bf16 pb = (__bf16)pk;
            afrag[k] = pb;
            lsum += (float)pb;
        }
#pragma unroll
        for (int ot = 0; ot < 4; ++ot) {
            bf16x8 b = *(const bf16x8*)(WhTu + (size_t)(ot * 16 + row16) * NN + jj);
            acc[ot] = __builtin_amdgcn_mfma_f32_16x16x32_bf16(afrag, b, acc[ot], 0, 0, 0);
        }
    }

    // full row-sum l_i: reduce over the 4 quads (disjoint j coverage)
    lsum += __shfl_xor(lsum, 16);
    lsum += __shfl_xor(lsum, 32);

    // C rows are quad*4+r but lsum is indexed by row16 — exchange via LDS
    __shared__ float l_lds[4][16];
    l_lds[wave][row16] = lsum;  // 4 lanes write identical value: benign
    __syncthreads();

#pragma unroll
    for (int ot = 0; ot < 4; ++ot) {
        int o = ot * 16 + row16;
#pragma unroll
        for (int r = 0; r < 4; ++r) {
            int   irow = blockIdx.x * 64 + wave * 16 + quad * 4 + r;
            float v    = acc[ot][r] / l_lds[wave][quad * 4 + r];
            float y    = v > 0.f ? v : __expf(v) - 1.f;  // ELU
            out[(size_t)irow * (HH * FOUT) + h * FOUT + o] = y;  // fp32 output
        }
    }
}

// ---------------------------------------------------------------------------
extern "C" void kernel_launch(void* const* d_in, const int* in_sizes, int n_in,
                              void* d_out, int out_size, void* d_ws, size_t ws_size,
                              hipStream_t stream) {
    const float* features = (const float*)d_in[0];
    const int*   adj      = (const int*)d_in[1];
    const float* W        = (const float*)d_in[2];
    const float* a_src    = (const float*)d_in[3];
    const float* a_dst    = (const float*)d_in[4];
    float*       out      = (float*)d_out;   // reference output dtype = fp32

    char* ws = (char*)d_ws;
    __hip_bfloat16* WT   = (__hip_bfloat16*)(ws);                      // 512 KB
    __hip_bfloat16* WhT  = (__hip_bfloat16*)(ws + 524288);             // 4 MB
    float*          srcv = (float*)(ws + 524288 + 4194304);            // 128 KB
    float*          dstv = (float*)(ws + 524288 + 4194304 + 131072);   // 128 KB

    k_transpose_w<<<dim3((HH * FIN * FOUT) / 256), 256, 0, stream>>>(W, WT);
    k_proj<<<dim3(NN / 64, HH), 256, 0, stream>>>(features, WT, a_src, a_dst,
                                                  WhT, srcv, dstv);
    k_flash<<<dim3(NN / 64, HH), 256, 0, stream>>>(adj, srcv, dstv, WhT, out);
}

// Round 5
// 306.487 us; speedup vs baseline: 1.1849x; 1.1849x over previous
//
#include <hip/hip_runtime.h>
#include <hip/hip_bf16.h>

typedef __bf16 bf16x8 __attribute__((ext_vector_type(8)));
typedef float  f32x4  __attribute__((ext_vector_type(4)));

#define HH    8
#define NN    4096
#define FIN   512
#define FOUT  64
#define ALPHA 0.2f

// ---------------------------------------------------------------------------
// k0: W[h][f][o] (fp32, 1 MB) -> WT[h][o][f] (bf16)
// ---------------------------------------------------------------------------
__global__ void k_transpose_w(const float* __restrict__ Wsrc,
                              __hip_bfloat16* __restrict__ WT) {
    int idx = blockIdx.x * blockDim.x + threadIdx.x;  // H*FIN*FOUT = 262144
    int h   = idx / (FIN * FOUT);
    int rem = idx % (FIN * FOUT);
    int f   = rem / FOUT;
    int o   = rem % FOUT;
    WT[((size_t)h * FOUT + o) * FIN + f] = __float2bfloat16(Wsrc[idx]);
}

// ---------------------------------------------------------------------------
// k_proj: block = 512 thr = 8 waves, one wave per HEAD, all sharing one
// 16-row feature tile staged once in LDS (bf16). Grid = 256 blocks.
// Feature HBM traffic: 8 MB (was 64 MB in the per-head-grid version).
// A-frag: lane holds A[m=lane&15][k=quad*8+j]; B-frag: B[k=quad*8+j][n=lane&15]
// C/D   : lane holds C[row=quad*4+r][col=lane&15]   (HW-verified layouts)
// ---------------------------------------------------------------------------
__global__ __launch_bounds__(512) void k_proj(
    const float* __restrict__ feat,
    const __hip_bfloat16* __restrict__ WT,
    const float* __restrict__ a_src,
    const float* __restrict__ a_dst,
    __hip_bfloat16* __restrict__ WhT,
    float* __restrict__ srcv, float* __restrict__ dstv) {
    // +8 bf16 pad -> row stride 1040 B: 2-way bank aliasing only (free)
    __shared__ alignas(16) __hip_bfloat16 lfeat[16][520];

    const int tid  = threadIdx.x;
    const int tile = blockIdx.x;          // 16 rows per block

    // Stage feat tile: 512 threads x 4 passes x float4, fp32 -> bf16
#pragma unroll
    for (int p = 0; p < 4; ++p) {
        int row = p * 4 + (tid >> 7);
        int col = (tid & 127) * 4;
        float4 f = *(const float4*)(feat + (size_t)(tile * 16 + row) * FIN + col);
        __hip_bfloat16* dst = &lfeat[row][col];
        dst[0] = __float2bfloat16(f.x); dst[1] = __float2bfloat16(f.y);
        dst[2] = __float2bfloat16(f.z); dst[3] = __float2bfloat16(f.w);
    }
    __syncthreads();

    const int h     = tid >> 6;           // head = wave index
    const int lane  = tid & 63;
    const int row16 = lane & 15;
    const int quad  = lane >> 4;
    const int nbase = tile * 16;

    const unsigned short* WTu = (const unsigned short*)WT + (size_t)h * FOUT * FIN;

    f32x4 acc[4] = {};
    for (int k0 = 0; k0 < FIN; k0 += 32) {
        bf16x8 a = *(const bf16x8*)&lfeat[row16][k0 + quad * 8];
#pragma unroll
        for (int ot = 0; ot < 4; ++ot) {
            bf16x8 b = *(const bf16x8*)(WTu + (size_t)(ot * 16 + row16) * FIN + k0 + quad * 8);
            acc[ot] = __builtin_amdgcn_mfma_f32_16x16x32_bf16(a, b, acc[ot], 0, 0, 0);
        }
    }

    // WhT[h][o][n] bf16 (B operand of the attention GEMM)
#pragma unroll
    for (int ot = 0; ot < 4; ++ot) {
        int o = ot * 16 + row16;
#pragma unroll
        for (int r = 0; r < 4; ++r) {
            int n = nbase + quad * 4 + r;
            WhT[((size_t)h * FOUT + o) * NN + n] = __float2bfloat16(acc[ot][r]);
        }
    }

    // src/dst logits from fp32 accumulators
    float asv[4], adv[4];
#pragma unroll
    for (int ot = 0; ot < 4; ++ot) {
        asv[ot] = a_src[h * FOUT + ot * 16 + row16];
        adv[ot] = a_dst[h * FOUT + ot * 16 + row16];
    }
#pragma unroll
    for (int r = 0; r < 4; ++r) {
        float ss = 0.f, dd = 0.f;
#pragma unroll
        for (int ot = 0; ot < 4; ++ot) {
            ss += acc[ot][r] * asv[ot];
            dd += acc[ot][r] * adv[ot];
        }
        ss += __shfl_xor(ss, 1); ss += __shfl_xor(ss, 2);
        ss += __shfl_xor(ss, 4); ss += __shfl_xor(ss, 8);
        dd += __shfl_xor(dd, 1); dd += __shfl_xor(dd, 2);
        dd += __shfl_xor(dd, 4); dd += __shfl_xor(dd, 8);
        if (row16 == 0) {
            int n = nbase + quad * 4 + r;
            srcv[h * NN + n] = ss;
            dstv[h * NN + n] = dd;
        }
    }
}

// ---------------------------------------------------------------------------
// k_flash: masked softmax attention + ELU, occupancy-first layout.
// Block = 1024 thr = 16 waves = 4 local heads x 4 j-segments (1024 cols each).
// Grid = (256 row-tiles, 2 head-groups) = 512 blocks, 8192 waves.
// Adjacency is read directly (int4 x2 per lane-iter) — NO scratch mask buffer
// (round-4's extra 2 MB workspace region overflowed ws_size and corrupted
// neighboring allocations -> post-timing divergence; stay at the proven 4.75 MB).
// Row-sum l via a 5th MFMA vs an all-ones B-frag (lands in C layout directly).
// Segments combine in-block via LDS; seg-0 waves write final output.
// launch_bounds (1024,4): <=128 VGPRs, no accumulator spills.
// ---------------------------------------------------------------------------
__global__ __launch_bounds__(1024, 4) void k_flash(
    const int* __restrict__ adj,
    const float* __restrict__ srcv, const float* __restrict__ dstv,
    const unsigned short* __restrict__ WhT,  // [H][FOUT][NN] bf16 bits
    float* __restrict__ out) {
    __shared__ float lds_acc[3][4][1024];
    __shared__ float lds_l[3][4][16];

    const int tid   = threadIdx.x;
    const int wv    = tid >> 6;              // 0..15
    const int lane  = tid & 63;
    const int row16 = lane & 15;
    const int quad  = lane >> 4;
    const int h4    = wv & 3;                // local head
    const int seg   = wv >> 2;               // j-segment 0..3
    const int h     = blockIdx.y * 4 + h4;
    const int tile  = blockIdx.x;
    const int i     = tile * 16 + row16;
    const int shl   = quad * 8;

    const float           si     = srcv[h * NN + i];
    const int*            adjrow = adj + (size_t)i * NN + seg * 1024;
    const float*          dsth   = dstv + h * NN + seg * 1024;
    const unsigned short* wh     = WhT + (size_t)h * FOUT * NN + seg * 1024;

    bf16x8 ones;
#pragma unroll
    for (int k = 0; k < 8; ++k) ones[k] = (__bf16)1.0f;

    f32x4 acc[4] = {};
    f32x4 accl   = {};

    for (int t = 0; t < 32; ++t) {
        int jj = t * 32 + shl;
        int4   a0 = *(const int4*)(adjrow + jj);
        int4   a1 = *(const int4*)(adjrow + jj + 4);
        float4 d0 = *(const float4*)(dsth + jj);
        float4 d1 = *(const float4*)(dsth + jj + 4);
        const float dv[8] = {d0.x, d0.y, d0.z, d0.w, d1.x, d1.y, d1.z, d1.w};
        const int   av[8] = {a0.x, a0.y, a0.z, a0.w, a1.x, a1.y, a1.z, a1.w};
        bf16x8 af;
#pragma unroll
        for (int k = 0; k < 8; ++k) {
            float tt = si + dv[k];
            float e  = fmaxf(tt, 0.f) + ALPHA * fminf(tt, 0.f);  // LeakyReLU
            float p  = av[k] > 0 ? __expf(e) : 0.f;
            af[k] = (__bf16)p;
        }
#pragma unroll
        for (int ot = 0; ot < 4; ++ot) {
            bf16x8 b = *(const bf16x8*)(wh + (size_t)(ot * 16 + row16) * NN + jj);
            acc[ot] = __builtin_amdgcn_mfma_f32_16x16x32_bf16(af, b, acc[ot], 0, 0, 0);
        }
        accl = __builtin_amdgcn_mfma_f32_16x16x32_bf16(af, ones, accl, 0, 0, 0);
    }

    if (seg > 0) {
        float* la = &lds_acc[seg - 1][h4][0];
#pragma unroll
        for (int ot = 0; ot < 4; ++ot)
#pragma unroll
            for (int r = 0; r < 4; ++r)
                la[(quad * 4 + r) * 64 + ot * 16 + row16] = acc[ot][r];
        if (row16 == 0) {
#pragma unroll
            for (int r = 0; r < 4; ++r)
                lds_l[seg - 1][h4][quad * 4 + r] = accl[r];
        }
    }
    __syncthreads();

    if (seg == 0) {
        const float* la0 = &lds_acc[0][h4][0];
        const float* la1 = &lds_acc[1][h4][0];
        const float* la2 = &lds_acc[2][h4][0];
#pragma unroll
        for (int r = 0; r < 4; ++r) {
            int   qr = quad * 4 + r;
            float l  = accl[r] + lds_l[0][h4][qr] + lds_l[1][h4][qr] + lds_l[2][h4][qr];
            float rl = 1.0f / l;
#pragma unroll
            for (int ot = 0; ot < 4; ++ot) {
                int   idx = qr * 64 + ot * 16 + row16;
                float v   = (acc[ot][r] + la0[idx] + la1[idx] + la2[idx]) * rl;
                float y   = v > 0.f ? v : __expf(v) - 1.f;  // ELU
                out[(size_t)(tile * 16 + qr) * (HH * FOUT) + h * FOUT + ot * 16 + row16] = y;
            }
        }
    }
}

// ---------------------------------------------------------------------------
extern "C" void kernel_launch(void* const* d_in, const int* in_sizes, int n_in,
                              void* d_out, int out_size, void* d_ws, size_t ws_size,
                              hipStream_t stream) {
    const float* features = (const float*)d_in[0];
    const int*   adj      = (const int*)d_in[1];
    const float* W        = (const float*)d_in[2];
    const float* a_src    = (const float*)d_in[3];
    const float* a_dst    = (const float*)d_in[4];
    float*       out      = (float*)d_out;   // reference output dtype = fp32

    // Workspace: 4.75 MB total (empirically within ws_size; round 4's 6.75 MB was not)
    char* ws = (char*)d_ws;
    __hip_bfloat16* WT   = (__hip_bfloat16*)(ws);                      // 512 KB
    __hip_bfloat16* WhT  = (__hip_bfloat16*)(ws + (512 << 10));        // 4 MB
    float*          srcv = (float*)(ws + (512 << 10) + (4 << 20));     // 128 KB
    float*          dstv = (float*)(ws + (512 << 10) + (4 << 20) + (128 << 10));  // 128 KB

    k_transpose_w<<<dim3((HH * FIN * FOUT) / 256), 256, 0, stream>>>(W, WT);
    k_proj<<<dim3(NN / 16), 512, 0, stream>>>(features, WT, a_src, a_dst,
                                              WhT, srcv, dstv);
    k_flash<<<dim3(NN / 16, 2), 1024, 0, stream>>>(adj, srcv, dstv,
                                                   (const unsigned short*)WhT, out);
}